// Round 5
// baseline (715.284 us; speedup 1.0000x reference)
//
#include <hip/hip_runtime.h>
#include <stdint.h>

#define NB 512
#define SL 1024
#define NT 64
#define NG 32   // groups of 16 batch rows
#define GR 16   // rows per group

typedef float f32x4 __attribute__((ext_vector_type(4)));
typedef float v2f  __attribute__((ext_vector_type(2)));
typedef short s16x8 __attribute__((ext_vector_type(8)));

__device__ __forceinline__ uint32_t bf16_rne(float x) {
    uint32_t u = __float_as_uint(x);
    return (u + 0x7fffu + ((u >> 16) & 1u)) >> 16;
}
// pack trunc(lo),trunc(hi) into one dword (lo in low16): v_perm_b32
__device__ __forceinline__ uint32_t pack_bf16_trunc(float lo, float hi) {
    return __builtin_amdgcn_perm(__float_as_uint(hi), __float_as_uint(lo), 0x07060302u);
}
// tag index assigned to B k-slot (chunk c, quad q, element e). Chosen so the
// MFMA C/D position (tile mi, reg) of tag t lands in the SAME lane that must
// supply t as a B element next step:  mi=(c<<1)|(e>>2), reg=e&3.
__device__ __forceinline__ int t_of(int c, int q, int e) {
    return 16 * (((c << 1) | (e >> 2))) + 4 * q + (e & 3);
}

__device__ __forceinline__ float wave_max6(float v) {
    #pragma unroll
    for (int off = 32; off >= 1; off >>= 1) v = fmaxf(v, __shfl_xor(v, off, 64));
    return v;
}
__device__ __forceinline__ float wave_sum_f(float v) {
    #pragma unroll
    for (int off = 32; off >= 1; off >>= 1) v += __shfl_xor(v, off, 64);
    return v;
}

// ============ Prepass: em4[g][i][lane][slot] = bf16(exp(emit)) permuted ============
// Block = (g, 16-step chunk). Reads emit[b][i][t] (contiguous 4KB rows), writes
// the scan's per-(step,lane) 32B records contiguously.
__global__ void __launch_bounds__(256) exp_permute_kernel(
    const float* __restrict__ emit, uint32_t* __restrict__ em4)
{
    __shared__ float tile[GR][16 * NT];  // 64 KB: [row][i_loc*64+t]
    const int g = blockIdx.x >> 6;
    const int i0 = (blockIdx.x & 63) << 4;
    const int tid = threadIdx.x;

    #pragma unroll 4
    for (int bb = 0; bb < GR; ++bb) {
        const float4* src = (const float4*)(emit + ((size_t)(GR * g + bb) * SL + i0) * NT);
        ((float4*)tile[bb])[tid] = src[tid];  // 256 thr x 16B = 4KB = 16 steps x 64 tags
    }
    __syncthreads();

    const int i_loc = tid >> 4;
    const int lane0 = (tid & 15) << 2;   // this thread covers lanes lane0..lane0+3
    uint4 outq[8];
    uint32_t* ov = (uint32_t*)outq;
    #pragma unroll
    for (int li = 0; li < 4; ++li) {
        const int lane = lane0 + li, q = lane >> 4, r = lane & 15;
        #pragma unroll
        for (int d = 0; d < 8; ++d) {          // dword d: chunk c=d>>2, pair dd=d&3
            const int c = d >> 2, dd = d & 3;
            const int t0 = t_of(c, q, 2 * dd + 0);
            const int t1 = t_of(c, q, 2 * dd + 1);
            const float f0 = __expf(tile[r][i_loc * NT + t0]);
            const float f1 = __expf(tile[r][i_loc * NT + t1]);
            ov[li * 8 + d] = bf16_rne(f0) | (bf16_rne(f1) << 16);
        }
    }
    uint4* dst = (uint4*)(em4 + (((size_t)(g * SL + i0 + i_loc) * 64) + lane0) * 8);
    #pragma unroll
    for (int k = 0; k < 8; ++k) dst[k] = outq[k];
}

// ============ Scan step: W' = (Ê^T·W) ∘ em, all in-register ============
template<bool DOREN>
__device__ __forceinline__ void scan_step(
    const s16x8 (&A)[4][2], uint4& B0, uint4& B1,
    uint4 em0, uint4 em1, int i, int len, float& logacc)
{
    union U { uint4 u; s16x8 h; };
    U b0; b0.u = B0; U b1; b1.u = B1;
    const f32x4 z = {0.f, 0.f, 0.f, 0.f};
    f32x4 acc[4];
    #pragma unroll
    for (int mi = 0; mi < 4; ++mi) {
        f32x4 t = __builtin_amdgcn_mfma_f32_16x16x32_bf16(A[mi][0], b0.h, z, 0, 0, 0);
        acc[mi]  = __builtin_amdgcn_mfma_f32_16x16x32_bf16(A[mi][1], b1.h, t, 0, 0, 0);
    }
    const uint32_t ed[8] = {em0.x, em0.y, em0.z, em0.w, em1.x, em1.y, em1.z, em1.w};
    v2f p[8];
    #pragma unroll
    for (int s = 0; s < 8; ++s) {          // em dword s pairs with acc[mi] regs rb,rb+1
        const int c = s >> 2, d = s & 3;
        const int mi = (c << 1) | (d >> 1);
        const int rb = (d & 1) * 2;
        const float elo = __uint_as_float(ed[s] << 16);
        const float ehi = __uint_as_float(ed[s] & 0xffff0000u);
        p[s].x = acc[mi][rb] * elo;
        p[s].y = acc[mi][rb + 1] * ehi;
    }
    const bool alive = (i < len);          // per-row freeze (row = lane&15)
    if (DOREN) {                           // exact power-of-2 per-row renorm
        float mx = 0.f;
        #pragma unroll
        for (int s = 0; s < 8; ++s) mx = fmaxf(mx, fmaxf(p[s].x, p[s].y));
        mx = fmaxf(mx, __shfl_xor(mx, 16, 64));
        mx = fmaxf(mx, __shfl_xor(mx, 32, 64));
        const int ex = (int)((__float_as_uint(mx) >> 23) & 0xffu);
        float sc = __uint_as_float((uint32_t)(254 - ex) << 23);  // 2^(127-ex)
        sc = alive ? sc : 1.0f;
        logacc += alive ? (float)(ex - 127) * 0.69314718055994530942f : 0.0f;
        #pragma unroll
        for (int s = 0; s < 8; ++s) { p[s].x *= sc; p[s].y *= sc; }
    }
    uint32_t nd[8];
    #pragma unroll
    for (int s = 0; s < 8; ++s) nd[s] = pack_bf16_trunc(p[s].x, p[s].y);
    B0.x = alive ? nd[0] : B0.x;  B0.y = alive ? nd[1] : B0.y;
    B0.z = alive ? nd[2] : B0.z;  B0.w = alive ? nd[3] : B0.w;
    B1.x = alive ? nd[4] : B1.x;  B1.y = alive ? nd[5] : B1.y;
    B1.z = alive ? nd[6] : B1.z;  B1.w = alive ? nd[7] : B1.w;
}

// ============ Scan kernel: one wave handles 16 batch rows ============
__global__ void __launch_bounds__(64) crf_scan16_kernel(
    const int* __restrict__ tags, const void* __restrict__ mask,
    const float* __restrict__ emit, const float* __restrict__ trans,
    const uint32_t* __restrict__ em4, float* __restrict__ out)
{
    const int g = blockIdx.x;
    const int lane = threadIdx.x;
    const int q = lane >> 4, r = lane & 15;
    const int b = GR * g + r;

    // ---- phase 0: gold score + length; 4 lanes (quads) split each row ----
    const unsigned char* mb = (const unsigned char*)mask;
    const bool mask_is_i32 = ((mb[1] | mb[2] | mb[3]) == 0);
    const int* trow = tags + (size_t)b * SL;
    float acc = 0.f; int cnt = 0;
    for (int ii = 0; ii < 256; ++ii) {
        const int i = q * 256 + ii;
        const int mk = mask_is_i32 ? (((const int*)mask)[(size_t)b * SL + i] != 0)
                                   : (mb[(size_t)b * SL + i] != 0);
        if (mk) {
            const int tg = trow[i];
            float val = emit[((size_t)b * SL + i) * NT + tg];
            if (i > 0) val += trans[trow[i - 1] * NT + tg];
            acc += val; cnt += 1;
        }
    }
    acc += __shfl_xor(acc, 16, 64); acc += __shfl_xor(acc, 32, 64);
    cnt += __shfl_xor(cnt, 16, 64); cnt += __shfl_xor(cnt, 32, 64);
    const float ts = acc;
    const int len = cnt;                      // per-row, replicated across quads
    int mx = len;
    #pragma unroll
    for (int off = 1; off <= 8; off <<= 1) mx = max(mx, __shfl_xor(mx, off, 64));
    const int nstep = __builtin_amdgcn_readfirstlane(mx) - 1;   // steps 1..nstep

    // ---- constant A fragments: Ê^T with the slot permutation baked in ----
    // A[mi][c] element e = bf16(exp(trans[p = t_of(c,q,e)][m = 16*mi + r]))
    s16x8 A[4][2];
    #pragma unroll
    for (int mi = 0; mi < 4; ++mi)
        #pragma unroll
        for (int c = 0; c < 2; ++c)
            #pragma unroll
            for (int e = 0; e < 8; ++e) {
                const int p = t_of(c, q, e);
                A[mi][c][e] = (short)bf16_rne(__expf(trans[p * NT + (16 * mi + r)]));
            }

    // ---- state init: B-frags ARE em4 at i=0 (= exp(emit[:,0]) permuted) ----
    const uint4* em_base = (const uint4*)em4 + (size_t)g * SL * 128 + (size_t)lane * 2;
    uint4 B0 = em_base[0], B1 = em_base[1];
    float logacc = 0.f;

    int i = 1;
    uint4 bufA[4][2], bufB[4][2];
    // preload 8 steps ahead (clamped loads are always in-bounds; masked rows
    // make out-of-range steps semantically dead)
    #pragma unroll
    for (int s = 0; s < 4; ++s) {
        int sa = min(i + s, SL - 1), sb = min(i + 4 + s, SL - 1);
        const uint4* pA = em_base + (size_t)sa * 128;
        const uint4* pB = em_base + (size_t)sb * 128;
        bufA[s][0] = pA[0]; bufA[s][1] = pA[1];
        bufB[s][0] = pB[0]; bufB[s][1] = pB[1];
    }
    const int nsuper = nstep >> 3;
    for (int sb = 0; sb < nsuper; ++sb) {
        scan_step<false>(A, B0, B1, bufA[0][0], bufA[0][1], i + 0, len, logacc);
        scan_step<false>(A, B0, B1, bufA[1][0], bufA[1][1], i + 1, len, logacc);
        scan_step<false>(A, B0, B1, bufA[2][0], bufA[2][1], i + 2, len, logacc);
        scan_step<true >(A, B0, B1, bufA[3][0], bufA[3][1], i + 3, len, logacc);
        #pragma unroll
        for (int s = 0; s < 4; ++s) {
            const uint4* pp = em_base + (size_t)min(i + 8 + s, SL - 1) * 128;
            bufA[s][0] = pp[0]; bufA[s][1] = pp[1];
        }
        scan_step<false>(A, B0, B1, bufB[0][0], bufB[0][1], i + 4, len, logacc);
        scan_step<false>(A, B0, B1, bufB[1][0], bufB[1][1], i + 5, len, logacc);
        scan_step<false>(A, B0, B1, bufB[2][0], bufB[2][1], i + 6, len, logacc);
        scan_step<true >(A, B0, B1, bufB[3][0], bufB[3][1], i + 7, len, logacc);
        #pragma unroll
        for (int s = 0; s < 4; ++s) {
            const uint4* pp = em_base + (size_t)min(i + 12 + s, SL - 1) * 128;
            bufB[s][0] = pp[0]; bufB[s][1] = pp[1];
        }
        i += 8;
    }
    for (; i <= nstep; ++i) {   // remainder: renorm every step (safe)
        const uint4* pp = em_base + (size_t)i * 128;
        scan_step<true>(A, B0, B1, pp[0], pp[1], i, len, logacc);
    }

    // ---- readout: log_z[r] = logacc + log(sum over 64 tags) ----
    const uint32_t fd[8] = {B0.x, B0.y, B0.z, B0.w, B1.x, B1.y, B1.z, B1.w};
    float sum = 0.f;
    #pragma unroll
    for (int s = 0; s < 8; ++s)
        sum += __uint_as_float(fd[s] << 16) + __uint_as_float(fd[s] & 0xffff0000u);
    sum += __shfl_xor(sum, 16, 64);
    sum += __shfl_xor(sum, 32, 64);
    const float log_z = logacc + __logf(sum);
    if (lane < GR) out[(size_t)g * GR + lane] = -(ts - log_z);
}

// ============ Fallback (R3, proven): used only if ws too small ============
__device__ __forceinline__ void dot2bf(float& acc, uint32_t a, uint32_t b) {
    asm("v_dot2_f32_bf16 %0, %1, %2, %0" : "+v"(acc) : "v"(a), "v"(b));
}
__global__ void __launch_bounds__(64) crf_fallback_kernel(
    const int* __restrict__ tags, const void* __restrict__ mask,
    const float* __restrict__ emit, const float* __restrict__ trans,
    float* __restrict__ out)
{
    const int b = blockIdx.x;
    const int lane = threadIdx.x;
    const float* erow = emit + (size_t)b * SL * NT;
    const int* trow = tags + (size_t)b * SL;
    const unsigned char* mb = (const unsigned char*)mask;
    const bool mask_is_i32 = ((mb[1] | mb[2] | mb[3]) == 0);
    float acc = 0.f; int cnt = 0;
    #pragma unroll
    for (int j = 0; j < 16; ++j) {
        const int i = lane + 64 * j;
        const int mk = mask_is_i32 ? (((const int*)mask)[(size_t)b * SL + i] != 0)
                                   : (mb[(size_t)b * SL + i] != 0);
        if (mk) {
            const int tg = trow[i];
            float val = erow[(size_t)i * NT + tg];
            if (i > 0) val += trans[trow[i - 1] * NT + tg];
            acc += val; cnt += 1;
        }
    }
    #pragma unroll
    for (int off = 32; off >= 1; off >>= 1) {
        acc += __shfl_xor(acc, off, 64);
        cnt += __shfl_xor(cnt, off, 64);
    }
    const float ts = acc; const int len = cnt;
    uint32_t Epk[NT / 2];
    #pragma unroll
    for (int m = 0; m < NT / 2; ++m) {
        uint32_t lo = bf16_rne(__expf(trans[(2 * m + 0) * NT + lane]));
        uint32_t hi = bf16_rne(__expf(trans[(2 * m + 1) * NT + lane]));
        Epk[m] = lo | (hi << 16);
    }
    __shared__ __align__(16) uint16_t vbuf16[NT];
    float d0 = erow[lane];
    float m0 = wave_max6(d0);
    float v = __expf(d0 - m0);
    float logacc = m0;
#define FSTEP(EX)                                                          \
    {                                                                      \
        vbuf16[lane] = (uint16_t)bf16_rne(v);                              \
        __builtin_amdgcn_wave_barrier();                                   \
        float a0=0.f,a1=0.f,a2=0.f,a3=0.f,a4=0.f,a5=0.f,a6=0.f,a7=0.f;     \
        const uint4* vb = (const uint4*)vbuf16;                            \
        _Pragma("unroll")                                                  \
        for (int rr = 0; rr < 8; rr += 2) {                                \
            uint4 q0 = vb[rr]; uint4 q1 = vb[rr + 1];                      \
            dot2bf(a0, q0.x, Epk[4*rr+0]); dot2bf(a1, q0.y, Epk[4*rr+1]);  \
            dot2bf(a2, q0.z, Epk[4*rr+2]); dot2bf(a3, q0.w, Epk[4*rr+3]);  \
            dot2bf(a4, q1.x, Epk[4*rr+4]); dot2bf(a5, q1.y, Epk[4*rr+5]);  \
            dot2bf(a6, q1.z, Epk[4*rr+6]); dot2bf(a7, q1.w, Epk[4*rr+7]);  \
        }                                                                  \
        v = (((a0+a1)+(a2+a3))+((a4+a5)+(a6+a7))) * (EX);                  \
    }
    const int nstep = len - 1, ngrp = nstep >> 2;
    int i = 1;
    float4 emq;
    if (ngrp > 0) {
        emq.x = erow[(i+0)*NT+lane]; emq.y = erow[(i+1)*NT+lane];
        emq.z = erow[(i+2)*NT+lane]; emq.w = erow[(i+3)*NT+lane];
    }
    for (int gg = 0; gg < ngrp; ++gg) {
        float ex0 = __expf(emq.x), ex1 = __expf(emq.y);
        float ex2 = __expf(emq.z), ex3 = __expf(emq.w);
        const int ip = i + 4;
        if (gg + 1 < ngrp) {
            emq.x = erow[(ip+0)*NT+lane]; emq.y = erow[(ip+1)*NT+lane];
            emq.z = erow[(ip+2)*NT+lane]; emq.w = erow[(ip+3)*NT+lane];
        }
        FSTEP(ex0) FSTEP(ex1) FSTEP(ex2) FSTEP(ex3)
        {
            uint32_t sb2 = __builtin_amdgcn_readfirstlane(__float_as_uint(v));
            int ex = (int)((sb2 >> 23) & 0xffu);
            v *= __uint_as_float((uint32_t)(254 - ex) << 23);
            logacc += (float)(ex - 127) * 0.69314718055994530942f;
        }
        i += 4;
    }
    for (; i < len; ++i) { float e = __expf(erow[i * NT + lane]); FSTEP(e) }
#undef FSTEP
    float sum = wave_sum_f(v);
    float log_z = logacc + __logf(sum);
    if (lane == 0) out[b] = -(ts - log_z);
}

extern "C" void kernel_launch(void* const* d_in, const int* in_sizes, int n_in,
                              void* d_out, int out_size, void* d_ws, size_t ws_size,
                              hipStream_t stream) {
    (void)in_sizes; (void)n_in; (void)out_size;
    const int*   tags  = (const int*)d_in[0];
    const void*  mask  = d_in[1];
    const float* emit  = (const float*)d_in[2];
    const float* trans = (const float*)d_in[3];
    float* out = (float*)d_out;

    const size_t EM4_BYTES = (size_t)NB * SL * NT * 2;  // 64 MiB
    if (ws_size >= EM4_BYTES) {
        exp_permute_kernel<<<dim3(NG * 64), dim3(256), 0, stream>>>(emit, (uint32_t*)d_ws);
        crf_scan16_kernel<<<dim3(NG), dim3(64), 0, stream>>>(
            tags, mask, emit, trans, (const uint32_t*)d_ws, out);
    } else {
        crf_fallback_kernel<<<dim3(NB), dim3(64), 0, stream>>>(tags, mask, emit, trans, out);
    }
}

// Round 6
// 522.058 us; speedup vs baseline: 1.3701x; 1.3701x over previous
//
#include <hip/hip_runtime.h>
#include <stdint.h>

#define NB 512
#define SL 1024
#define NT 64
#define NG 32   // groups of 16 batch rows
#define GR 16   // rows per group

typedef float f32x4 __attribute__((ext_vector_type(4)));
typedef float v2f  __attribute__((ext_vector_type(2)));
typedef short s16x8 __attribute__((ext_vector_type(8)));

__device__ __forceinline__ uint32_t bf16_rne(float x) {
    uint32_t u = __float_as_uint(x);
    return (u + 0x7fffu + ((u >> 16) & 1u)) >> 16;
}
// pack trunc(lo),trunc(hi) into one dword (lo in low16)
__device__ __forceinline__ uint32_t pack_bf16_trunc(float lo, float hi) {
    return __builtin_amdgcn_perm(__float_as_uint(hi), __float_as_uint(lo), 0x07060302u);
}
// tag index assigned to B k-slot (chunk c, quad q, element e) — HW-verified in R5
__device__ __forceinline__ int t_of(int c, int q, int e) {
    return 16 * (((c << 1) | (e >> 2))) + 4 * q + (e & 3);
}

__device__ __forceinline__ float wave_max6(float v) {
    #pragma unroll
    for (int off = 32; off >= 1; off >>= 1) v = fmaxf(v, __shfl_xor(v, off, 64));
    return v;
}
__device__ __forceinline__ float wave_sum_f(float v) {
    #pragma unroll
    for (int off = 32; off >= 1; off >>= 1) v += __shfl_xor(v, off, 64);
    return v;
}

// ============ Prepass (unchanged from R5, proven) ============
__global__ void __launch_bounds__(256) exp_permute_kernel(
    const float* __restrict__ emit, uint32_t* __restrict__ em4)
{
    __shared__ float tile[GR][16 * NT];  // 64 KB
    const int g = blockIdx.x >> 6;
    const int i0 = (blockIdx.x & 63) << 4;
    const int tid = threadIdx.x;

    #pragma unroll 4
    for (int bb = 0; bb < GR; ++bb) {
        const float4* src = (const float4*)(emit + ((size_t)(GR * g + bb) * SL + i0) * NT);
        ((float4*)tile[bb])[tid] = src[tid];
    }
    __syncthreads();

    const int i_loc = tid >> 4;
    const int lane0 = (tid & 15) << 2;
    uint4 outq[8];
    uint32_t* ov = (uint32_t*)outq;
    #pragma unroll
    for (int li = 0; li < 4; ++li) {
        const int lane = lane0 + li, q = lane >> 4, r = lane & 15;
        #pragma unroll
        for (int d = 0; d < 8; ++d) {
            const int c = d >> 2, dd = d & 3;
            const int t0 = t_of(c, q, 2 * dd + 0);
            const int t1 = t_of(c, q, 2 * dd + 1);
            const float f0 = __expf(tile[r][i_loc * NT + t0]);
            const float f1 = __expf(tile[r][i_loc * NT + t1]);
            ov[li * 8 + d] = bf16_rne(f0) | (bf16_rne(f1) << 16);
        }
    }
    uint4* dst = (uint4*)(em4 + (((size_t)(g * SL + i0 + i_loc) * 64) + lane0) * 8);
    #pragma unroll
    for (int k = 0; k < 8; ++k) dst[k] = outq[k];
}

// ============ One scan step ============
// FREEZE: per-row hold for dead rows. MEASURE: sample magnitude + launch
// cross-quad max shuffles. APPLY: consume deferred max, exact pow2 rescale.
template<bool FREEZE, bool MEASURE, bool APPLY>
__device__ __forceinline__ void sstep(
    const s16x8 (&A)[4][2], uint4& B0, uint4& B1,
    const uint4& em0, const uint4& em1,
    int i, int len, float& logacc,
    float& mx, float& m1, float& m2, float& m3)
{
    union U { uint4 u; s16x8 h; };
    U b0; b0.u = B0; U b1; b1.u = B1;
    const f32x4 z = {0.f, 0.f, 0.f, 0.f};
    f32x4 acc[4];
    #pragma unroll
    for (int mi = 0; mi < 4; ++mi) {
        f32x4 t = __builtin_amdgcn_mfma_f32_16x16x32_bf16(A[mi][0], b0.h, z, 0, 0, 0);
        acc[mi]  = __builtin_amdgcn_mfma_f32_16x16x32_bf16(A[mi][1], b1.h, t, 0, 0, 0);
    }
    const uint32_t ed[8] = {em0.x, em0.y, em0.z, em0.w, em1.x, em1.y, em1.z, em1.w};
    v2f p[8];
    #pragma unroll
    for (int s = 0; s < 8; ++s) {
        const int c = s >> 2, d = s & 3;
        const int mi = (c << 1) | (d >> 1);
        const int rb = (d & 1) * 2;
        v2f e; e.x = __uint_as_float(ed[s] << 16);
               e.y = __uint_as_float(ed[s] & 0xffff0000u);
        v2f a; a.x = acc[mi][rb]; a.y = acc[mi][rb + 1];
        p[s] = a * e;
    }
    if (MEASURE) {
        float mm = fmaxf(p[0].x, p[0].y);
        #pragma unroll
        for (int s = 1; s < 8; ++s) mm = fmaxf(mm, fmaxf(p[s].x, p[s].y));
        mx = mm;
        m1 = __shfl_xor(mm, 16, 64);   // 3 parallel DS ops; results consumed
        m2 = __shfl_xor(mm, 32, 64);   // next step -> latency hidden
        m3 = __shfl_xor(mm, 48, 64);
    }
    const bool alive = FREEZE ? (i < len) : true;
    if (APPLY) {
        const float mm = fmaxf(fmaxf(mx, m1), fmaxf(m2, m3));
        const int ex = (int)((__float_as_uint(mm) >> 23) & 0xffu);
        const float sc = __uint_as_float((uint32_t)(254 - ex) << 23);  // 2^(127-ex)
        v2f scp; scp.x = sc; scp.y = sc;
        #pragma unroll
        for (int s = 0; s < 8; ++s) p[s] *= scp;
        logacc += alive ? (float)(ex - 127) * 0.69314718055994530942f : 0.0f;
    }
    uint32_t nd[8];
    #pragma unroll
    for (int s = 0; s < 8; ++s) nd[s] = pack_bf16_trunc(p[s].x, p[s].y);
    if (FREEZE) {
        B0.x = alive ? nd[0] : B0.x;  B0.y = alive ? nd[1] : B0.y;
        B0.z = alive ? nd[2] : B0.z;  B0.w = alive ? nd[3] : B0.w;
        B1.x = alive ? nd[4] : B1.x;  B1.y = alive ? nd[5] : B1.y;
        B1.z = alive ? nd[6] : B1.z;  B1.w = alive ? nd[7] : B1.w;
    } else {
        B0.x = nd[0]; B0.y = nd[1]; B0.z = nd[2]; B0.w = nd[3];
        B1.x = nd[4]; B1.y = nd[5]; B1.z = nd[6]; B1.w = nd[7];
    }
}

// ============ Scan kernel: one wave handles 16 batch rows ============
__global__ void __launch_bounds__(64) crf_scan16_kernel(
    const int* __restrict__ tags, const void* __restrict__ mask,
    const float* __restrict__ emit, const float* __restrict__ trans,
    const uint32_t* __restrict__ em4, float* __restrict__ out)
{
    const int g = blockIdx.x;
    const int lane = threadIdx.x;
    const int q = lane >> 4, r = lane & 15;
    const int b = GR * g + r;

    // ---- phase 0: gold score + length (branchless, pipelinable) ----
    const unsigned char* mb = (const unsigned char*)mask;
    const bool mask_is_i32 = ((mb[1] | mb[2] | mb[3]) == 0);
    const int* trow = tags + (size_t)b * SL;
    float acc = 0.f; int cnt = 0;
    #pragma unroll 8
    for (int ii = 0; ii < 256; ++ii) {
        const int i = q * 256 + ii;
        const int mk = mask_is_i32 ? (((const int*)mask)[(size_t)b * SL + i] != 0)
                                   : (mb[(size_t)b * SL + i] != 0);
        const int tg = trow[i];
        const int tp = trow[i > 0 ? i - 1 : 0];
        const float ev = emit[((size_t)b * SL + i) * NT + tg];
        const float tv = (i > 0) ? trans[tp * NT + tg] : 0.0f;
        acc += mk ? (ev + tv) : 0.0f;
        cnt += mk;
    }
    acc += __shfl_xor(acc, 16, 64); acc += __shfl_xor(acc, 32, 64);
    cnt += __shfl_xor(cnt, 16, 64); cnt += __shfl_xor(cnt, 32, 64);
    const float ts = acc;
    const int len = cnt;                         // per-row, replicated across quads
    int mn = len, mx_l = len;
    #pragma unroll
    for (int off = 1; off <= 8; off <<= 1) {
        mn   = min(mn,   __shfl_xor(mn,   off, 64));
        mx_l = max(mx_l, __shfl_xor(mx_l, off, 64));
    }
    const int minlen = __builtin_amdgcn_readfirstlane(mn);
    const int nstep  = __builtin_amdgcn_readfirstlane(mx_l) - 1;  // steps 1..nstep

    // ---- constant A fragments (verified layout, R5) ----
    s16x8 A[4][2];
    #pragma unroll
    for (int mi = 0; mi < 4; ++mi)
        #pragma unroll
        for (int c = 0; c < 2; ++c)
            #pragma unroll
            for (int e = 0; e < 8; ++e) {
                const int p = t_of(c, q, e);
                A[mi][c][e] = (short)bf16_rne(__expf(trans[p * NT + (16 * mi + r)]));
            }

    // ---- state init: record 0 = exp(emit[:,0]) permuted ----
    const uint4* em_base = (const uint4*)em4 + (size_t)g * SL * 128 + (size_t)lane * 2;
    uint4 B0 = em_base[0], B1 = em_base[1];
    float logacc = 0.f;
    float dmx = 1.f, dm1 = 1.f, dm2 = 1.f, dm3 = 1.f;  // deferred renorm state

    // ---- 12-deep register prefetch ring (slack = 8 steps > HBM latency) ----
    uint4 bufA[4][2], bufB[4][2], bufC[4][2];
    #pragma unroll
    for (int s = 0; s < 4; ++s) {
        const uint4* pA = em_base + (size_t)min(1 + s,     SL - 1) * 128;
        const uint4* pB = em_base + (size_t)min(1 + 4 + s, SL - 1) * 128;
        const uint4* pC = em_base + (size_t)min(1 + 8 + s, SL - 1) * 128;
        bufA[s][0] = pA[0]; bufA[s][1] = pA[1];
        bufB[s][0] = pB[0]; bufB[s][1] = pB[1];
        bufC[s][0] = pC[0]; bufC[s][1] = pC[1];
    }
    int i = 1;

#define SUB4(F, BUF, IBASE)                                                          \
    sstep<F, false, false>(A, B0, B1, BUF[0][0], BUF[0][1], (IBASE) + 0, len,        \
                           logacc, dmx, dm1, dm2, dm3);                              \
    sstep<F, false, false>(A, B0, B1, BUF[1][0], BUF[1][1], (IBASE) + 1, len,        \
                           logacc, dmx, dm1, dm2, dm3);                              \
    sstep<F, true,  false>(A, B0, B1, BUF[2][0], BUF[2][1], (IBASE) + 2, len,        \
                           logacc, dmx, dm1, dm2, dm3);                              \
    sstep<F, false, true >(A, B0, B1, BUF[3][0], BUF[3][1], (IBASE) + 3, len,        \
                           logacc, dmx, dm1, dm2, dm3);

#define RELOAD(BUF, IBASE)                                                           \
    {                                                                                \
        _Pragma("unroll")                                                            \
        for (int s = 0; s < 4; ++s) {                                                \
            const uint4* pp = em_base + (size_t)min((IBASE) + s, SL - 1) * 128;      \
            BUF[s][0] = pp[0]; BUF[s][1] = pp[1];                                    \
        }                                                                            \
    }

#define BLOCK12(F)                                                                   \
    {                                                                                \
        SUB4(F, bufA, i)      RELOAD(bufA, i + 12)                                   \
        SUB4(F, bufB, i + 4)  RELOAD(bufB, i + 16)                                   \
        SUB4(F, bufC, i + 8)  RELOAD(bufC, i + 20)                                   \
        i += 12;                                                                     \
    }

    while (i + 11 < minlen) BLOCK12(false)   // all rows alive: no freeze checks
    while (i <= nstep)      BLOCK12(true)    // tail: freeze; overshoot steps are
                                             // all-dead (held B), clamped loads
#undef BLOCK12
#undef RELOAD
#undef SUB4

    // ---- readout ----
    const uint32_t fd[8] = {B0.x, B0.y, B0.z, B0.w, B1.x, B1.y, B1.z, B1.w};
    float sum = 0.f;
    #pragma unroll
    for (int s = 0; s < 8; ++s)
        sum += __uint_as_float(fd[s] << 16) + __uint_as_float(fd[s] & 0xffff0000u);
    sum += __shfl_xor(sum, 16, 64);
    sum += __shfl_xor(sum, 32, 64);
    const float log_z = logacc + __logf(sum);
    if (lane < GR) out[(size_t)g * GR + lane] = -(ts - log_z);
}

// ============ Fallback (R3, proven): used only if ws too small ============
__device__ __forceinline__ void dot2bf(float& acc, uint32_t a, uint32_t b) {
    asm("v_dot2_f32_bf16 %0, %1, %2, %0" : "+v"(acc) : "v"(a), "v"(b));
}
__global__ void __launch_bounds__(64) crf_fallback_kernel(
    const int* __restrict__ tags, const void* __restrict__ mask,
    const float* __restrict__ emit, const float* __restrict__ trans,
    float* __restrict__ out)
{
    const int b = blockIdx.x;
    const int lane = threadIdx.x;
    const float* erow = emit + (size_t)b * SL * NT;
    const int* trow = tags + (size_t)b * SL;
    const unsigned char* mb = (const unsigned char*)mask;
    const bool mask_is_i32 = ((mb[1] | mb[2] | mb[3]) == 0);
    float acc = 0.f; int cnt = 0;
    #pragma unroll
    for (int j = 0; j < 16; ++j) {
        const int i = lane + 64 * j;
        const int mk = mask_is_i32 ? (((const int*)mask)[(size_t)b * SL + i] != 0)
                                   : (mb[(size_t)b * SL + i] != 0);
        if (mk) {
            const int tg = trow[i];
            float val = erow[(size_t)i * NT + tg];
            if (i > 0) val += trans[trow[i - 1] * NT + tg];
            acc += val; cnt += 1;
        }
    }
    #pragma unroll
    for (int off = 32; off >= 1; off >>= 1) {
        acc += __shfl_xor(acc, off, 64);
        cnt += __shfl_xor(cnt, off, 64);
    }
    const float ts = acc; const int len = cnt;
    uint32_t Epk[NT / 2];
    #pragma unroll
    for (int m = 0; m < NT / 2; ++m) {
        uint32_t lo = bf16_rne(__expf(trans[(2 * m + 0) * NT + lane]));
        uint32_t hi = bf16_rne(__expf(trans[(2 * m + 1) * NT + lane]));
        Epk[m] = lo | (hi << 16);
    }
    __shared__ __align__(16) uint16_t vbuf16[NT];
    float d0 = erow[lane];
    float m0 = wave_max6(d0);
    float v = __expf(d0 - m0);
    float logacc = m0;
#define FSTEP(EX)                                                          \
    {                                                                      \
        vbuf16[lane] = (uint16_t)bf16_rne(v);                              \
        __builtin_amdgcn_wave_barrier();                                   \
        float a0=0.f,a1=0.f,a2=0.f,a3=0.f,a4=0.f,a5=0.f,a6=0.f,a7=0.f;     \
        const uint4* vb = (const uint4*)vbuf16;                            \
        _Pragma("unroll")                                                  \
        for (int rr = 0; rr < 8; rr += 2) {                                \
            uint4 q0 = vb[rr]; uint4 q1 = vb[rr + 1];                      \
            dot2bf(a0, q0.x, Epk[4*rr+0]); dot2bf(a1, q0.y, Epk[4*rr+1]);  \
            dot2bf(a2, q0.z, Epk[4*rr+2]); dot2bf(a3, q0.w, Epk[4*rr+3]);  \
            dot2bf(a4, q1.x, Epk[4*rr+4]); dot2bf(a5, q1.y, Epk[4*rr+5]);  \
            dot2bf(a6, q1.z, Epk[4*rr+6]); dot2bf(a7, q1.w, Epk[4*rr+7]);  \
        }                                                                  \
        v = (((a0+a1)+(a2+a3))+((a4+a5)+(a6+a7))) * (EX);                  \
    }
    const int nstep = len - 1, ngrp = nstep >> 2;
    int i = 1;
    float4 emq;
    if (ngrp > 0) {
        emq.x = erow[(i+0)*NT+lane]; emq.y = erow[(i+1)*NT+lane];
        emq.z = erow[(i+2)*NT+lane]; emq.w = erow[(i+3)*NT+lane];
    }
    for (int gg = 0; gg < ngrp; ++gg) {
        float ex0 = __expf(emq.x), ex1 = __expf(emq.y);
        float ex2 = __expf(emq.z), ex3 = __expf(emq.w);
        const int ip = i + 4;
        if (gg + 1 < ngrp) {
            emq.x = erow[(ip+0)*NT+lane]; emq.y = erow[(ip+1)*NT+lane];
            emq.z = erow[(ip+2)*NT+lane]; emq.w = erow[(ip+3)*NT+lane];
        }
        FSTEP(ex0) FSTEP(ex1) FSTEP(ex2) FSTEP(ex3)
        {
            uint32_t sb2 = __builtin_amdgcn_readfirstlane(__float_as_uint(v));
            int ex = (int)((sb2 >> 23) & 0xffu);
            v *= __uint_as_float((uint32_t)(254 - ex) << 23);
            logacc += (float)(ex - 127) * 0.69314718055994530942f;
        }
        i += 4;
    }
    for (; i < len; ++i) { float e = __expf(erow[i * NT + lane]); FSTEP(e) }
#undef FSTEP
    float sum = wave_sum_f(v);
    float log_z = logacc + __logf(sum);
    if (lane == 0) out[b] = -(ts - log_z);
}

extern "C" void kernel_launch(void* const* d_in, const int* in_sizes, int n_in,
                              void* d_out, int out_size, void* d_ws, size_t ws_size,
                              hipStream_t stream) {
    (void)in_sizes; (void)n_in; (void)out_size;
    const int*   tags  = (const int*)d_in[0];
    const void*  mask  = d_in[1];
    const float* emit  = (const float*)d_in[2];
    const float* trans = (const float*)d_in[3];
    float* out = (float*)d_out;

    const size_t EM4_BYTES = (size_t)NB * SL * NT * 2;  // 64 MiB
    if (ws_size >= EM4_BYTES) {
        exp_permute_kernel<<<dim3(NG * 64), dim3(256), 0, stream>>>(emit, (uint32_t*)d_ws);
        crf_scan16_kernel<<<dim3(NG), dim3(64), 0, stream>>>(
            tags, mask, emit, trans, (const uint32_t*)d_ws, out);
    } else {
        crf_fallback_kernel<<<dim3(NB), dim3(64), 0, stream>>>(tags, mask, emit, trans, out);
    }
}